// Round 1
// baseline (91.556 us; speedup 1.0000x reference)
//
#include <hip/hip_runtime.h>
#include <hip/hip_bf16.h>
#include <math.h>

// Problem constants (from reference)
#define B_   64
#define C_   256
#define H_   56
#define W_   56
#define L_   8
#define OUT_ 4096
#define KDIM (L_ * C_)   // 2048

// ---------------------------------------------------------------------------
// Kernel 1: RoI bilinear sample (2x2 grid) + maxpool -> pooled (B, L*C)
// grid = B*L blocks, 256 threads (1 channel each)
// ---------------------------------------------------------------------------
__global__ __launch_bounds__(256) void roi_pool_kernel(
    const float* __restrict__ feat,      // (B,C,H,W)
    const float* __restrict__ lms,       // (B, L*2)
    float* __restrict__ pooled)          // (B, L*C)
{
    const int blid = blockIdx.x;         // 0 .. B*L-1
    const int b = blid >> 3;             // / L_
    const int l = blid & 7;              // % L_
    const int c = threadIdx.x;           // 0..255

    // Landmark -> normalized grid center (reference math):
    // lm = landmark/224*7 ; t = -1 + 2*lm/7  ->  t = -1 + landmark/112
    const float lx = lms[b * (L_ * 2) + 2 * l];
    const float ly = lms[b * (L_ * 2) + 2 * l + 1];
    const float tx = -1.0f + lx * (1.0f / 112.0f);
    const float ty = -1.0f + ly * (1.0f / 112.0f);
    const float Aaff = 2.0f / 7.0f;      // ROI/CROP

    // base = {(2i+1)/2 - 1} = {-0.5, +0.5}
    float wx[2], wy[2];
    int x0[2], x1[2], y0[2], y1[2];
    #pragma unroll
    for (int j = 0; j < 2; ++j) {
        const float base = (j == 0) ? -0.5f : 0.5f;
        const float gx = Aaff * base + tx;
        const float gy = Aaff * base + ty;
        // align_corners=False unnormalize + border clip
        float fx = ((gx + 1.0f) * (float)W_ - 1.0f) * 0.5f;
        float fy = ((gy + 1.0f) * (float)H_ - 1.0f) * 0.5f;
        fx = fminf(fmaxf(fx, 0.0f), (float)(W_ - 1));
        fy = fminf(fmaxf(fy, 0.0f), (float)(H_ - 1));
        const float fx0 = floorf(fx);
        const float fy0 = floorf(fy);
        wx[j] = fx - fx0;
        wy[j] = fy - fy0;
        x0[j] = (int)fx0;
        y0[j] = (int)fy0;
        x1[j] = min(x0[j] + 1, W_ - 1);
        y1[j] = min(y0[j] + 1, H_ - 1);
    }

    const float* fb = feat + ((size_t)(b * C_ + c)) * (H_ * W_);
    float mx = -INFINITY;
    #pragma unroll
    for (int i = 0; i < 2; ++i) {            // y index
        const float* r0 = fb + y0[i] * W_;
        const float* r1 = fb + y1[i] * W_;
        const float wyi = wy[i];
        #pragma unroll
        for (int j = 0; j < 2; ++j) {        // x index
            const float v00 = r0[x0[j]];
            const float v01 = r0[x1[j]];
            const float v10 = r1[x0[j]];
            const float v11 = r1[x1[j]];
            const float wxj = wx[j];
            const float top = v00 + wxj * (v01 - v00);
            const float bot = v10 + wxj * (v11 - v10);
            const float val = top + wyi * (bot - top);
            mx = fmaxf(mx, val);
        }
    }
    pooled[(size_t)(b * L_ + l) * C_ + c] = mx;
}

// ---------------------------------------------------------------------------
// Kernel 2: out = relu(pooled @ W^T + b)   (64 x 2048) x (4096 x 2048)^T
// grid = OUT_/GN blocks (256), 256 threads. Thread: n = t%GN, mg = t/GN,
// computes 4 consecutive m values for its n.
// ---------------------------------------------------------------------------
#define GN 16
#define GK 32

__global__ __launch_bounds__(256) void gemm_bias_relu_kernel(
    const float* __restrict__ flat,   // (B, KDIM)
    const float* __restrict__ Wl,     // (OUT_, KDIM)
    const float* __restrict__ bl,     // (OUT_)
    float* __restrict__ out)          // (B, OUT_)
{
    __shared__ float Af[B_][GK + 4];  // +4 pad: keeps float4 alignment, breaks bank stride
    __shared__ float Wf[GN][GK + 4];

    const int t  = threadIdx.x;
    const int n0 = blockIdx.x * GN;
    const int n  = t % GN;            // 0..15
    const int mg = t / GN;            // 0..15  -> m = mg*4 + i

    float acc[4] = {0.f, 0.f, 0.f, 0.f};

    for (int k0 = 0; k0 < KDIM; k0 += GK) {
        // Stage A tile: 64 x 32 = 2048 elems, 8 per thread, coalesced in k
        #pragma unroll
        for (int i = 0; i < 8; ++i) {
            const int li = t + i * 256;
            const int m  = li >> 5;       // /32
            const int kk = li & 31;
            Af[m][kk] = flat[(size_t)m * KDIM + k0 + kk];
        }
        // Stage W tile: 16 x 32 = 512 elems, 2 per thread
        #pragma unroll
        for (int i = 0; i < 2; ++i) {
            const int li = t + i * 256;
            const int nn = li >> 5;
            const int kk = li & 31;
            Wf[nn][kk] = Wl[(size_t)(n0 + nn) * KDIM + k0 + kk];
        }
        __syncthreads();

        #pragma unroll
        for (int kk = 0; kk < GK; kk += 4) {
            const float4 w4 = *(const float4*)&Wf[n][kk];
            #pragma unroll
            for (int i = 0; i < 4; ++i) {
                const float4 a4 = *(const float4*)&Af[mg * 4 + i][kk];
                acc[i] = fmaf(a4.x, w4.x, acc[i]);
                acc[i] = fmaf(a4.y, w4.y, acc[i]);
                acc[i] = fmaf(a4.z, w4.z, acc[i]);
                acc[i] = fmaf(a4.w, w4.w, acc[i]);
            }
        }
        __syncthreads();
    }

    const float bias = bl[n0 + n];
    #pragma unroll
    for (int i = 0; i < 4; ++i) {
        const int m = mg * 4 + i;
        const float v = acc[i] + bias;
        out[(size_t)m * OUT_ + n0 + n] = v > 0.0f ? v : 0.0f;
    }
}

// ---------------------------------------------------------------------------
extern "C" void kernel_launch(void* const* d_in, const int* in_sizes, int n_in,
                              void* d_out, int out_size, void* d_ws, size_t ws_size,
                              hipStream_t stream) {
    const float* features  = (const float*)d_in[0];  // (64,256,56,56)
    const float* landmarks = (const float*)d_in[1];  // (64,16)
    const float* W_lin     = (const float*)d_in[2];  // (4096,2048)
    const float* b_lin     = (const float*)d_in[3];  // (4096,)
    float* out = (float*)d_out;                      // (64,4096)

    float* pooled = (float*)d_ws;                    // (64,2048) = 512 KB

    roi_pool_kernel<<<B_ * L_, 256, 0, stream>>>(features, landmarks, pooled);
    gemm_bias_relu_kernel<<<OUT_ / GN, 256, 0, stream>>>(pooled, W_lin, b_lin, out);
}

// Round 2
// 87.961 us; speedup vs baseline: 1.0409x; 1.0409x over previous
//
#include <hip/hip_runtime.h>
#include <hip/hip_bf16.h>
#include <math.h>

// Problem constants (from reference)
#define B_   64
#define C_   256
#define H_   56
#define W_   56
#define L_   8
#define OUT_ 4096
#define KDIM (L_ * C_)   // 2048

// ---------------------------------------------------------------------------
// Kernel 1: RoI bilinear sample (2x2 grid) + maxpool -> pooled (B, L*C)
// grid = B*L blocks, 512 threads: thread = (c, jx); jx = x-column of the 2x2.
// Each thread does the 2 y-samples for its x-column (8 scattered loads),
// then a __shfl_xor(1) max combines the two columns. 4 waves/SIMD for MLP.
// ---------------------------------------------------------------------------
__global__ __launch_bounds__(512) void roi_pool_kernel(
    const float* __restrict__ feat,      // (B,C,H,W)
    const float* __restrict__ lms,       // (B, L*2)
    float* __restrict__ pooled)          // (B, L*C)
{
    const int blid = blockIdx.x;         // 0 .. B*L-1
    const int b = blid >> 3;             // / L_
    const int l = blid & 7;              // % L_
    const int tid = threadIdx.x;
    const int c  = tid >> 1;             // 0..255
    const int jx = tid & 1;              // x column (0 or 1)

    // lm = landmark/224*7 ; t = -1 + 2*lm/7  ->  t = -1 + landmark/112
    const float lx = lms[b * (L_ * 2) + 2 * l];
    const float ly = lms[b * (L_ * 2) + 2 * l + 1];
    const float tx = -1.0f + lx * (1.0f / 112.0f);
    const float ty = -1.0f + ly * (1.0f / 112.0f);
    const float Aaff = 2.0f / 7.0f;      // ROI/CROP

    // base = {-0.5, +0.5}
    float wx_j; int x0_j, x1_j;
    {
        const float base = (jx == 0) ? -0.5f : 0.5f;
        const float gx = Aaff * base + tx;
        float fx = ((gx + 1.0f) * (float)W_ - 1.0f) * 0.5f;
        fx = fminf(fmaxf(fx, 0.0f), (float)(W_ - 1));
        const float fx0 = floorf(fx);
        wx_j = fx - fx0;
        x0_j = (int)fx0;
        x1_j = min(x0_j + 1, W_ - 1);
    }
    float wy[2]; int y0[2], y1[2];
    #pragma unroll
    for (int i = 0; i < 2; ++i) {
        const float base = (i == 0) ? -0.5f : 0.5f;
        const float gy = Aaff * base + ty;
        float fy = ((gy + 1.0f) * (float)H_ - 1.0f) * 0.5f;
        fy = fminf(fmaxf(fy, 0.0f), (float)(H_ - 1));
        const float fy0 = floorf(fy);
        wy[i] = fy - fy0;
        y0[i] = (int)fy0;
        y1[i] = min(y0[i] + 1, H_ - 1);
    }

    const float* fb = feat + ((size_t)(b * C_ + c)) * (H_ * W_);
    float mx = -INFINITY;
    #pragma unroll
    for (int i = 0; i < 2; ++i) {
        const float* r0 = fb + y0[i] * W_;
        const float* r1 = fb + y1[i] * W_;
        const float v00 = r0[x0_j];
        const float v01 = r0[x1_j];
        const float v10 = r1[x0_j];
        const float v11 = r1[x1_j];
        const float top = v00 + wx_j * (v01 - v00);
        const float bot = v10 + wx_j * (v11 - v10);
        const float val = top + wy[i] * (bot - top);
        mx = fmaxf(mx, val);
    }
    // combine the two x columns (lane pairs)
    mx = fmaxf(mx, __shfl_xor(mx, 1));
    if (jx == 0)
        pooled[(size_t)(b * L_ + l) * C_ + c] = mx;
}

// ---------------------------------------------------------------------------
// Kernel 2: split-K partial GEMM.  partial[ks][m][n] = sum_{k in chunk} A[m,k]W[n,k]
// Block: 256 thr = 4 waves. lane = n (64 n per block), wave -> 16 m rows.
// W tile staged in LDS (XOR-swizzled, read 1x b128 per 64 FMAs);
// A read via wave-uniform loads (SMEM/L1 pipe, LDS untouched).
// grid = (OUT_/64) * KSPLIT = 512 blocks -> 2 blocks/CU.
// ---------------------------------------------------------------------------
#define KSPLIT 8
#define KCHUNK (KDIM / KSPLIT)   // 256
#define KC 64                    // k per staged tile
#define NT 64                    // n per block

__global__ __launch_bounds__(256) void gemm_partial_kernel(
    const float* __restrict__ flat,   // (B, KDIM)
    const float* __restrict__ Wl,     // (OUT_, KDIM)
    float* __restrict__ partial)      // (KSPLIT, B_, OUT_)
{
    __shared__ float Wlds[NT][KC];    // 16 KB, XOR-swizzled rows

    const int t    = threadIdx.x;
    const int lane = t & 63;
    const int wv   = t >> 6;          // 0..3
    const int bid  = blockIdx.x;
    const int ntile = bid >> 3;       // 0..63
    const int ks    = bid & 7;        // k-split id
    const int n0    = ntile * NT;
    const int kbase = ks * KCHUNK;
    const int mbase = wv * 16;

    float acc[16];
    #pragma unroll
    for (int m = 0; m < 16; ++m) acc[m] = 0.0f;

    for (int kc = 0; kc < KCHUNK; kc += KC) {
        // Stage W tile: 64 rows x 64 k = 4096 floats; 4x float4 per thread.
        #pragma unroll
        for (int i = 0; i < 4; ++i) {
            const int idx = t + i * 256;        // 0..1023
            const int r   = idx >> 4;           // row 0..63
            const int cg  = idx & 15;           // col group (x4 floats)
            const float4 g = *(const float4*)&Wl[(size_t)(n0 + r) * KDIM + kbase + kc + cg * 4];
            const int col = (cg * 4) ^ ((r & 7) << 2);   // T2 swizzle (f32 b128)
            *(float4*)&Wlds[r][col] = g;
        }
        __syncthreads();

        const float* abase = flat + kbase + kc;  // wave-uniform base
        #pragma unroll 4
        for (int kk = 0; kk < KC; kk += 4) {
            const int col = kk ^ ((lane & 7) << 2);
            const float4 w4 = *(const float4*)&Wlds[lane][col];
            float4 am[16];
            #pragma unroll
            for (int m = 0; m < 16; ++m)
                am[m] = *(const float4*)(abase + (size_t)(mbase + m) * KDIM + kk);
            // component-outer order: dep-chain distance 16 on each acc[m]
            #pragma unroll
            for (int m = 0; m < 16; ++m) acc[m] = fmaf(am[m].x, w4.x, acc[m]);
            #pragma unroll
            for (int m = 0; m < 16; ++m) acc[m] = fmaf(am[m].y, w4.y, acc[m]);
            #pragma unroll
            for (int m = 0; m < 16; ++m) acc[m] = fmaf(am[m].z, w4.z, acc[m]);
            #pragma unroll
            for (int m = 0; m < 16; ++m) acc[m] = fmaf(am[m].w, w4.w, acc[m]);
        }
        __syncthreads();
    }

    #pragma unroll
    for (int m = 0; m < 16; ++m)
        partial[((size_t)ks * B_ + mbase + m) * OUT_ + n0 + lane] = acc[m];
}

// ---------------------------------------------------------------------------
// Kernel 3: out[m][n] = relu(sum_ks partial[ks][m][n] + bias[n]), float4-wide.
// ---------------------------------------------------------------------------
__global__ __launch_bounds__(256) void reduce_bias_relu_kernel(
    const float* __restrict__ partial,  // (KSPLIT, B_, OUT_)
    const float* __restrict__ bl,       // (OUT_)
    float* __restrict__ out)            // (B_, OUT_)
{
    const int idx = blockIdx.x * 256 + threadIdx.x;  // over B_*OUT_/4 = 65536
    const int n4 = idx & (OUT_ / 4 - 1);             // 0..1023
    const int m  = idx >> 10;                        // 0..63

    float4 s = *(const float4*)&bl[n4 * 4];
    #pragma unroll
    for (int ks = 0; ks < KSPLIT; ++ks) {
        const float4 p = *(const float4*)&partial[((size_t)ks * B_ + m) * OUT_ + n4 * 4];
        s.x += p.x; s.y += p.y; s.z += p.z; s.w += p.w;
    }
    s.x = fmaxf(s.x, 0.0f); s.y = fmaxf(s.y, 0.0f);
    s.z = fmaxf(s.z, 0.0f); s.w = fmaxf(s.w, 0.0f);
    *(float4*)&out[(size_t)m * OUT_ + n4 * 4] = s;
}

// ---------------------------------------------------------------------------
extern "C" void kernel_launch(void* const* d_in, const int* in_sizes, int n_in,
                              void* d_out, int out_size, void* d_ws, size_t ws_size,
                              hipStream_t stream) {
    const float* features  = (const float*)d_in[0];  // (64,256,56,56)
    const float* landmarks = (const float*)d_in[1];  // (64,16)
    const float* W_lin     = (const float*)d_in[2];  // (4096,2048)
    const float* b_lin     = (const float*)d_in[3];  // (4096,)
    float* out = (float*)d_out;                      // (64,4096)

    float* pooled  = (float*)d_ws;                   // (64,2048)   = 512 KB
    float* partial = (float*)d_ws + (size_t)B_ * KDIM; // (8,64,4096) = 8 MB

    roi_pool_kernel<<<B_ * L_, 512, 0, stream>>>(features, landmarks, pooled);
    gemm_partial_kernel<<<(OUT_ / NT) * KSPLIT, 256, 0, stream>>>(pooled, W_lin, partial);
    reduce_bias_relu_kernel<<<(B_ * OUT_ / 4) / 256, 256, 0, stream>>>(partial, b_lin, out);
}

// Round 3
// 33.037 us; speedup vs baseline: 2.7713x; 2.6625x over previous
//
#include <hip/hip_runtime.h>
#include <hip/hip_bf16.h>
#include <math.h>

// Problem constants (from reference)
#define B_   64
#define C_   256
#define H_   56
#define W_   56
#define L_   8
#define OUT_ 4096
#define KDIM 2048

typedef __attribute__((ext_vector_type(8))) short short8v;   // 8 bf16 (4 VGPRs)
typedef __attribute__((ext_vector_type(4))) float float4v;   // MFMA C/D

// fp32 -> bf16 bits, round-to-nearest-even (inputs finite)
__device__ __forceinline__ unsigned short f2bf(float f) {
    unsigned u = __builtin_bit_cast(unsigned, f);
    return (unsigned short)((u + 0x7fffu + ((u >> 16) & 1u)) >> 16);
}

// ---------------------------------------------------------------------------
// Kernel 1: RoI bilinear sample (2x2 grid) + maxpool -> pooled bf16 (B, L*C)
// grid = B*L blocks, 512 threads: thread = (c, jx); jx = x-column of the 2x2.
// ---------------------------------------------------------------------------
__global__ __launch_bounds__(512) void roi_pool_kernel(
    const float* __restrict__ feat,      // (B,C,H,W)
    const float* __restrict__ lms,       // (B, L*2)
    unsigned short* __restrict__ pooled) // (B, L*C) bf16 bits
{
    const int blid = blockIdx.x;         // 0 .. B*L-1
    const int b = blid >> 3;
    const int l = blid & 7;
    const int tid = threadIdx.x;
    const int c  = tid >> 1;             // 0..255
    const int jx = tid & 1;              // x column (0 or 1)

    // t = -1 + landmark/112 ; grid spacing A = 2/7
    const float lx = lms[b * (L_ * 2) + 2 * l];
    const float ly = lms[b * (L_ * 2) + 2 * l + 1];
    const float tx = -1.0f + lx * (1.0f / 112.0f);
    const float ty = -1.0f + ly * (1.0f / 112.0f);
    const float Aaff = 2.0f / 7.0f;

    float wx_j; int x0_j, x1_j;
    {
        const float base = (jx == 0) ? -0.5f : 0.5f;
        const float gx = Aaff * base + tx;
        float fx = ((gx + 1.0f) * (float)W_ - 1.0f) * 0.5f;
        fx = fminf(fmaxf(fx, 0.0f), (float)(W_ - 1));
        const float fx0 = floorf(fx);
        wx_j = fx - fx0;
        x0_j = (int)fx0;
        x1_j = min(x0_j + 1, W_ - 1);
    }
    float wy[2]; int y0[2], y1[2];
    #pragma unroll
    for (int i = 0; i < 2; ++i) {
        const float base = (i == 0) ? -0.5f : 0.5f;
        const float gy = Aaff * base + ty;
        float fy = ((gy + 1.0f) * (float)H_ - 1.0f) * 0.5f;
        fy = fminf(fmaxf(fy, 0.0f), (float)(H_ - 1));
        const float fy0 = floorf(fy);
        wy[i] = fy - fy0;
        y0[i] = (int)fy0;
        y1[i] = min(y0[i] + 1, H_ - 1);
    }

    const float* fb = feat + ((size_t)(b * C_ + c)) * (H_ * W_);
    float mx = -INFINITY;
    #pragma unroll
    for (int i = 0; i < 2; ++i) {
        const float* r0 = fb + y0[i] * W_;
        const float* r1 = fb + y1[i] * W_;
        const float v00 = r0[x0_j];
        const float v01 = r0[x1_j];
        const float v10 = r1[x0_j];
        const float v11 = r1[x1_j];
        const float top = v00 + wx_j * (v01 - v00);
        const float bot = v10 + wx_j * (v11 - v10);
        const float val = top + wy[i] * (bot - top);
        mx = fmaxf(mx, val);
    }
    mx = fmaxf(mx, __shfl_xor(mx, 1));
    if (jx == 0)
        pooled[(size_t)(b * L_ + l) * C_ + c] = f2bf(mx);
}

// ---------------------------------------------------------------------------
// Kernel 2: out = relu(A @ W^T + b) via bf16 MFMA, fused epilogue.
// A: pooled bf16 (64 x 2048, L2-resident). W: fp32 (4096 x 2048), streamed
// from HBM exactly once, converted to bf16 in-register (B^T fragment form).
// Block: 256 thr = 4 waves; block tile M=64 x N=16; waves split K 4 ways
// (512 each = 16 MFMA k-steps); LDS reduce + bias + relu.
// grid = OUT_/16 = 256 blocks -> 1 block/CU, W read spread over all CUs.
// ---------------------------------------------------------------------------
__global__ __launch_bounds__(256) void gemm_mfma_kernel(
    const unsigned short* __restrict__ Abf,  // (64, 2048) bf16 bits
    const float* __restrict__ Wl,            // (4096, 2048) fp32
    const float* __restrict__ bl,            // (4096)
    float* __restrict__ out)                 // (64, 4096) fp32
{
    __shared__ float red[4][64][16];   // 16 KB reduction buffer

    const int t    = threadIdx.x;
    const int lane = t & 63;
    const int wv   = t >> 6;           // k-quarter 0..3
    const int n0   = blockIdx.x * 16;

    const int rs  = lane & 15;         // A-row / B-col within tile
    const int oct = lane >> 4;         // k-octet selector (8 contiguous k)

    float4v acc[4];
    #pragma unroll
    for (int mt = 0; mt < 4; ++mt) acc[mt] = (float4v){0.f, 0.f, 0.f, 0.f};

    const float* wrow = Wl + (size_t)(n0 + rs) * KDIM;   // this lane's W row
    const int kq0 = wv * (KDIM / 4);                     // wave's K chunk base

    #pragma unroll 4
    for (int ks = 0; ks < 16; ++ks) {
        const int koff = kq0 + ks * 32 + oct * 8;        // 8 contiguous k

        // B fragment: 8 fp32 from W row (coalesced 16-row x 64B+ segments)
        const float4 w0 = *(const float4*)(wrow + koff);
        const float4 w1 = *(const float4*)(wrow + koff + 4);
        short8v bfrag;
        bfrag[0] = (short)f2bf(w0.x); bfrag[1] = (short)f2bf(w0.y);
        bfrag[2] = (short)f2bf(w0.z); bfrag[3] = (short)f2bf(w0.w);
        bfrag[4] = (short)f2bf(w1.x); bfrag[5] = (short)f2bf(w1.y);
        bfrag[6] = (short)f2bf(w1.z); bfrag[7] = (short)f2bf(w1.w);

        // A fragments (bf16, from L2-resident pooled)
        #pragma unroll
        for (int mt = 0; mt < 4; ++mt) {
            const short8v afrag =
                *(const short8v*)((const short*)Abf + (size_t)(mt * 16 + rs) * KDIM + koff);
            acc[mt] = __builtin_amdgcn_mfma_f32_16x16x32_bf16(afrag, bfrag, acc[mt], 0, 0, 0);
        }
    }

    // C/D layout: col = lane&15 (=rs), row = oct*4 + reg
    #pragma unroll
    for (int mt = 0; mt < 4; ++mt)
        #pragma unroll
        for (int r = 0; r < 4; ++r)
            red[wv][mt * 16 + oct * 4 + r][rs] = acc[mt][r];

    __syncthreads();

    // Reduce 4 k-quarters, add bias, relu, store. 1024 outputs / 256 thr.
    #pragma unroll
    for (int i = 0; i < 4; ++i) {
        const int idx = t + i * 256;
        const int m = idx >> 4;
        const int n = idx & 15;
        float s = red[0][m][n] + red[1][m][n] + red[2][m][n] + red[3][m][n];
        s += bl[n0 + n];
        out[(size_t)m * OUT_ + n0 + n] = s > 0.0f ? s : 0.0f;
    }
}

// ---------------------------------------------------------------------------
extern "C" void kernel_launch(void* const* d_in, const int* in_sizes, int n_in,
                              void* d_out, int out_size, void* d_ws, size_t ws_size,
                              hipStream_t stream) {
    const float* features  = (const float*)d_in[0];  // (64,256,56,56)
    const float* landmarks = (const float*)d_in[1];  // (64,16)
    const float* W_lin     = (const float*)d_in[2];  // (4096,2048)
    const float* b_lin     = (const float*)d_in[3];  // (4096,)
    float* out = (float*)d_out;                      // (64,4096)

    unsigned short* pooled = (unsigned short*)d_ws;  // (64,2048) bf16 = 256 KB

    roi_pool_kernel<<<B_ * L_, 512, 0, stream>>>(features, landmarks, pooled);
    gemm_mfma_kernel<<<OUT_ / 16, 256, 0, stream>>>(pooled, W_lin, b_lin, out);
}

// Round 4
// 30.538 us; speedup vs baseline: 2.9981x; 1.0818x over previous
//
#include <hip/hip_runtime.h>
#include <hip/hip_bf16.h>
#include <math.h>

// Problem constants (from reference)
#define B_   64
#define C_   256
#define H_   56
#define W_   56
#define L_   8
#define OUT_ 4096
#define KDIM 2048

typedef __attribute__((ext_vector_type(8))) short short8v;   // 8 bf16 (4 VGPRs)
typedef __attribute__((ext_vector_type(4))) float float4v;   // MFMA C/D

// 8-byte value with only 4-byte alignment guarantee (x0 can be odd).
struct __attribute__((packed, aligned(4))) F2 { float x, y; };

// fp32 -> bf16 bits, RNE (single values; pairs use __bf16 casts for cvt_pk)
__device__ __forceinline__ unsigned short f2bf(float f) {
    unsigned u = __builtin_bit_cast(unsigned, f);
    return (unsigned short)((u + 0x7fffu + ((u >> 16) & 1u)) >> 16);
}

// ---------------------------------------------------------------------------
// Kernel 1: RoI bilinear sample (2x2 grid) + maxpool -> pooled bf16 (B, L*C)
// grid = B*L = 512 blocks, 512 threads: thread = (c, i); i = y-row of the 2x2.
// Each thread does both x-columns for its y-sample via 4 packed 8B loads
// (x1 = x0+1 is contiguous), then __shfl_xor(1) maxes across the two y rows.
// Block swizzle: all 8 landmarks of a batch on the same XCD (L2 row dedupe).
// ---------------------------------------------------------------------------
__global__ __launch_bounds__(512) void roi_pool_kernel(
    const float* __restrict__ feat,      // (B,C,H,W)
    const float* __restrict__ lms,       // (B, L*2)
    unsigned short* __restrict__ pooled) // (B, L*C) bf16 bits
{
    // XCD-affinity: round-robin dispatch puts block j on XCD j%8.
    // Map XCD x -> batches 8x..8x+7 (all 8 landmarks of a batch together).
    const int xcd  = blockIdx.x & 7;
    const int idx  = blockIdx.x >> 3;
    const int work = xcd * 64 + idx;     // 0..511
    const int b = work >> 3;
    const int l = work & 7;

    const int tid = threadIdx.x;
    const int c  = tid >> 1;             // 0..255
    const int iy = tid & 1;              // y sample index (0 or 1)

    // t = -1 + landmark/112 ; grid spacing A = 2/7
    const float lx = lms[b * (L_ * 2) + 2 * l];
    const float ly = lms[b * (L_ * 2) + 2 * l + 1];
    const float tx = -1.0f + lx * (1.0f / 112.0f);
    const float ty = -1.0f + ly * (1.0f / 112.0f);
    const float Aaff = 2.0f / 7.0f;

    // Both x windows for this thread
    float wx[2]; int xb[2]; bool xhi[2];
    #pragma unroll
    for (int j = 0; j < 2; ++j) {
        const float base = (j == 0) ? -0.5f : 0.5f;
        const float gx = Aaff * base + tx;
        float fx = ((gx + 1.0f) * (float)W_ - 1.0f) * 0.5f;
        fx = fminf(fmaxf(fx, 0.0f), (float)(W_ - 1));
        const float fx0 = floorf(fx);
        wx[j] = fx - fx0;
        const int x0 = (int)fx0;
        xhi[j] = (x0 == W_ - 1);         // clamped: wx==0, v01 weight is 0
        xb[j]  = xhi[j] ? (W_ - 2) : x0; // packed load base (in-row, no OOB)
    }
    // This thread's y sample
    float wyv; int y0v, y1v;
    {
        const float base = (iy == 0) ? -0.5f : 0.5f;
        const float gy = Aaff * base + ty;
        float fy = ((gy + 1.0f) * (float)H_ - 1.0f) * 0.5f;
        fy = fminf(fmaxf(fy, 0.0f), (float)(H_ - 1));
        const float fy0 = floorf(fy);
        wyv = fy - fy0;
        y0v = (int)fy0;
        y1v = min(y0v + 1, H_ - 1);
    }

    const float* fb = feat + ((size_t)(b * C_ + c)) * (H_ * W_);
    const float* r0 = fb + y0v * W_;
    const float* r1 = fb + y1v * W_;

    // 4 packed loads (independent -> all in flight together)
    const F2 p00 = *(const F2*)(r0 + xb[0]);
    const F2 p01 = *(const F2*)(r0 + xb[1]);
    const F2 p10 = *(const F2*)(r1 + xb[0]);
    const F2 p11 = *(const F2*)(r1 + xb[1]);

    // bilinear for x window j: v0 = row[x0], v1 = row[x0+1] (y if clamped, wx=0)
    float mx;
    {
        const float v00 = xhi[0] ? p00.y : p00.x;
        const float v10 = xhi[0] ? p10.y : p10.x;
        const float top = v00 + wx[0] * (p00.y - v00);
        const float bot = v10 + wx[0] * (p10.y - v10);
        mx = top + wyv * (bot - top);
    }
    {
        const float v00 = xhi[1] ? p01.y : p01.x;
        const float v10 = xhi[1] ? p11.y : p11.x;
        const float top = v00 + wx[1] * (p01.y - v00);
        const float bot = v10 + wx[1] * (p11.y - v10);
        const float val = top + wyv * (bot - top);
        mx = fmaxf(mx, val);
    }
    // combine the two y rows (lane pairs)
    mx = fmaxf(mx, __shfl_xor(mx, 1));
    if (iy == 0)
        pooled[(size_t)(b * L_ + l) * C_ + c] = f2bf(mx);
}

// ---------------------------------------------------------------------------
// Kernel 2: out = relu(A @ W^T + b) via bf16 MFMA, fused epilogue.
// A: pooled bf16 (64 x 2048, L2-resident). W: fp32 (4096 x 2048), streamed
// from HBM exactly once, converted to bf16 in-register (compiler fuses the
// __bf16 casts into v_cvt_pk_bf16_f32). Block: 512 thr = 8 waves; tile
// M=64 x N=16; waves split K 8 ways (256 each = 8 MFMA k-steps).
// grid = OUT_/16 = 256 blocks -> 1 block/CU, 8 waves/CU of W-stream MLP.
// ---------------------------------------------------------------------------
__global__ __launch_bounds__(512) void gemm_mfma_kernel(
    const unsigned short* __restrict__ Abf,  // (64, 2048) bf16 bits
    const float* __restrict__ Wl,            // (4096, 2048) fp32
    const float* __restrict__ bl,            // (4096)
    float* __restrict__ out)                 // (64, 4096) fp32
{
    __shared__ float red[8][64][16];   // 32 KB reduction buffer

    const int t    = threadIdx.x;
    const int lane = t & 63;
    const int wv   = t >> 6;           // k-eighth 0..7
    const int n0   = blockIdx.x * 16;

    const int rs  = lane & 15;         // A-row / W-row within tile (fragment)
    const int oct = lane >> 4;         // k-octet selector (8 contiguous k)

    float4v acc[4];
    #pragma unroll
    for (int mt = 0; mt < 4; ++mt) acc[mt] = (float4v){0.f, 0.f, 0.f, 0.f};

    const float* wrow = Wl + (size_t)(n0 + rs) * KDIM;   // this lane's W row
    const int kq0 = wv * (KDIM / 8);                     // wave's K chunk base

    #pragma unroll 4
    for (int ks = 0; ks < 8; ++ks) {
        const int koff = kq0 + ks * 32 + oct * 8;        // 8 contiguous k

        // B fragment: 8 fp32 from W row; 4 octs cover 128B contiguous/row.
        const float4 w0 = *(const float4*)(wrow + koff);
        const float4 w1 = *(const float4*)(wrow + koff + 4);
        short8v bfrag;
        bfrag[0] = __builtin_bit_cast(short, (__bf16)w0.x);
        bfrag[1] = __builtin_bit_cast(short, (__bf16)w0.y);
        bfrag[2] = __builtin_bit_cast(short, (__bf16)w0.z);
        bfrag[3] = __builtin_bit_cast(short, (__bf16)w0.w);
        bfrag[4] = __builtin_bit_cast(short, (__bf16)w1.x);
        bfrag[5] = __builtin_bit_cast(short, (__bf16)w1.y);
        bfrag[6] = __builtin_bit_cast(short, (__bf16)w1.z);
        bfrag[7] = __builtin_bit_cast(short, (__bf16)w1.w);

        // A fragments (bf16, L2-resident pooled)
        #pragma unroll
        for (int mt = 0; mt < 4; ++mt) {
            const short8v afrag =
                *(const short8v*)((const short*)Abf + (size_t)(mt * 16 + rs) * KDIM + koff);
            acc[mt] = __builtin_amdgcn_mfma_f32_16x16x32_bf16(afrag, bfrag, acc[mt], 0, 0, 0);
        }
    }

    // C/D layout: col(n) = lane&15, row-within-16 = oct*4 + reg
    #pragma unroll
    for (int mt = 0; mt < 4; ++mt)
        #pragma unroll
        for (int r = 0; r < 4; ++r)
            red[wv][mt * 16 + oct * 4 + r][rs] = acc[mt][r];

    __syncthreads();

    // Reduce 8 k-chunks, add bias, relu, store. 1024 outputs / 512 thr.
    #pragma unroll
    for (int i = 0; i < 2; ++i) {
        const int idx = t + i * 512;
        const int m = idx >> 4;
        const int n = idx & 15;
        float s = 0.0f;
        #pragma unroll
        for (int q = 0; q < 8; ++q) s += red[q][m][n];
        s += bl[n0 + n];
        out[(size_t)m * OUT_ + n0 + n] = s > 0.0f ? s : 0.0f;
    }
}

// ---------------------------------------------------------------------------
extern "C" void kernel_launch(void* const* d_in, const int* in_sizes, int n_in,
                              void* d_out, int out_size, void* d_ws, size_t ws_size,
                              hipStream_t stream) {
    const float* features  = (const float*)d_in[0];  // (64,256,56,56)
    const float* landmarks = (const float*)d_in[1];  // (64,16)
    const float* W_lin     = (const float*)d_in[2];  // (4096,2048)
    const float* b_lin     = (const float*)d_in[3];  // (4096,)
    float* out = (float*)d_out;                      // (64,4096)

    unsigned short* pooled = (unsigned short*)d_ws;  // (64,2048) bf16 = 256 KB

    roi_pool_kernel<<<B_ * L_, 512, 0, stream>>>(features, landmarks, pooled);
    gemm_mfma_kernel<<<OUT_ / 16, 512, 0, stream>>>(pooled, W_lin, b_lin, out);
}